// Round 1
// baseline (124.138 us; speedup 1.0000x reference)
//
#include <hip/hip_runtime.h>
#include <math.h>

#define NQ 14
#define DIM (1 << NQ)      // 16384
#define NL 2
#define NBATCH 64
#define TPB 1024

// One block per batch element. Full 16384-amp complex state lives in dynamic
// LDS (128 KiB; gfx950 has 160 KiB/CU -> 1 block/CU, but grid is only 64
// blocks anyway since BATCH=64).
//
// Algebraic fusion: per (layer,q) the net single-qubit operator is
//   U = RX(t2) * RZ(t1) * RX(t0) * RZ(x2) * RY(x1)
// (gates on different qubits commute, so the reference's per-qubit loops
// collapse to one fused 2x2 per qubit per layer). CNOT chain is 13 in-place
// swap sweeps (pure permutation, no flops).
__global__ __launch_bounds__(TPB) void qsim_kernel(
    const float* __restrict__ x,
    const float* __restrict__ thetas,
    float* __restrict__ out)
{
    extern __shared__ float2 s[];              // DIM complex amplitudes
    __shared__ float2 gmat[NL * NQ * 4];       // fused 2x2: g00,g01,g10,g11
    __shared__ float redbuf[TPB / 64];

    const int b   = blockIdx.x;
    const int tid = threadIdx.x;
    const float xv = x[b];

    // init |0...0>
    for (int k = tid; k < DIM; k += TPB) s[k] = make_float2(0.f, 0.f);
    if (tid == 0) s[0] = make_float2(1.f, 0.f);

    // build fused gates: one thread per (layer,q)
    if (tid < NL * NQ) {
        const int layer = tid / NQ, q = tid % NQ;
        const float x1 = asinf(xv);
        const float x2 = acosf(xv * xv);
        float c1, s1; sincosf(0.5f * x1, &s1, &c1);
        // g = RY(x1)  (real matrix [[c,-s],[s,c]])
        float2 g[4];
        g[0] = make_float2(c1, 0.f);  g[1] = make_float2(-s1, 0.f);
        g[2] = make_float2(s1, 0.f);  g[3] = make_float2(c1, 0.f);
        // left-multiply by RZ(t): row0 *= (c - i s), row1 *= (c + i s)
        auto lmul_rz = [&](float t) {
            float cc, ss; sincosf(0.5f * t, &ss, &cc);
            for (int col = 0; col < 2; ++col) {
                float2 a = g[col];
                float2 d = g[2 + col];
                g[col]     = make_float2(cc * a.x + ss * a.y, cc * a.y - ss * a.x);
                g[2 + col] = make_float2(cc * d.x - ss * d.y, cc * d.y + ss * d.x);
            }
        };
        // left-multiply by RX(t) = [[c, -i s], [-i s, c]]
        auto lmul_rx = [&](float t) {
            float cc, ss; sincosf(0.5f * t, &ss, &cc);
            for (int col = 0; col < 2; ++col) {
                float2 a = g[col];
                float2 d = g[2 + col];
                g[col]     = make_float2(cc * a.x + ss * d.y,  cc * a.y - ss * d.x);
                g[2 + col] = make_float2(ss * a.y + cc * d.x, -ss * a.x + cc * d.y);
            }
        };
        const float t0 = thetas[(layer * NQ + q) * 3 + 0];
        const float t1 = thetas[(layer * NQ + q) * 3 + 1];
        const float t2 = thetas[(layer * NQ + q) * 3 + 2];
        lmul_rz(x2); lmul_rx(t0); lmul_rz(t1); lmul_rx(t2);
        gmat[tid * 4 + 0] = g[0]; gmat[tid * 4 + 1] = g[1];
        gmat[tid * 4 + 2] = g[2]; gmat[tid * 4 + 3] = g[3];
    }
    __syncthreads();

    for (int layer = 0; layer < NL; ++layer) {
        // fused single-qubit sweep per qubit
        for (int q = 0; q < NQ; ++q) {
            const int bpos = NQ - 1 - q;       // qubit q <-> bit (NQ-1-q)
            const int m = 1 << bpos;
            const float2 g00 = gmat[(layer * NQ + q) * 4 + 0];
            const float2 g01 = gmat[(layer * NQ + q) * 4 + 1];
            const float2 g10 = gmat[(layer * NQ + q) * 4 + 2];
            const float2 g11 = gmat[(layer * NQ + q) * 4 + 3];
            for (int p = tid; p < DIM / 2; p += TPB) {
                const int k0 = ((p & ~(m - 1)) << 1) | (p & (m - 1));
                const int k1 = k0 | m;
                const float2 a = s[k0];
                const float2 c = s[k1];
                float2 n0, n1;
                n0.x = g00.x * a.x - g00.y * a.y + g01.x * c.x - g01.y * c.y;
                n0.y = g00.x * a.y + g00.y * a.x + g01.x * c.y + g01.y * c.x;
                n1.x = g10.x * a.x - g10.y * a.y + g11.x * c.x - g11.y * c.y;
                n1.y = g10.x * a.y + g10.y * a.x + g11.x * c.y + g11.y * c.x;
                s[k0] = n0;
                s[k1] = n1;
            }
            __syncthreads();
        }
        // CNOT chain c -> c+1: swap (control=1,target=0) <-> (control=1,target=1)
        for (int c = 0; c < NQ - 1; ++c) {
            const int bt = NQ - 1 - (c + 1);   // target bit (control bit = bt+1)
            for (int p = tid; p < DIM / 4; p += TPB) {
                const int low  = p & ((1 << bt) - 1);
                const int high = p >> bt;
                const int k  = (high << (bt + 2)) | (1 << (bt + 1)) | low;
                const int k2 = k | (1 << bt);
                const float2 tmp = s[k];
                s[k]  = s[k2];
                s[k2] = tmp;
            }
            __syncthreads();
        }
    }

    // <Z^14> = sum_k (-1)^popcount(k) * |amp_k|^2
    float acc = 0.f;
    for (int k = tid; k < DIM; k += TPB) {
        const float2 a = s[k];
        const float p2 = a.x * a.x + a.y * a.y;
        acc += (__popc(k) & 1) ? -p2 : p2;
    }
    for (int off = 32; off > 0; off >>= 1)
        acc += __shfl_down(acc, off, 64);
    const int lane = tid & 63, wid = tid >> 6;
    if (lane == 0) redbuf[wid] = acc;
    __syncthreads();
    if (tid == 0) {
        float tot = 0.f;
        for (int w = 0; w < TPB / 64; ++w) tot += redbuf[w];
        out[b] = tot;
    }
}

extern "C" void kernel_launch(void* const* d_in, const int* in_sizes, int n_in,
                              void* d_out, int out_size, void* d_ws, size_t ws_size,
                              hipStream_t stream) {
    const float* x      = (const float*)d_in[0];
    const float* thetas = (const float*)d_in[1];
    float* out          = (float*)d_out;
    const size_t shmem = (size_t)DIM * sizeof(float2);   // 128 KiB dynamic LDS
    qsim_kernel<<<NBATCH, TPB, shmem, stream>>>(x, thetas, out);
}

// Round 2
// 97.537 us; speedup vs baseline: 1.2727x; 1.2727x over previous
//
#include <hip/hip_runtime.h>
#include <math.h>

#define NQ 14
#define DIM (1 << NQ)      // 16384
#define NL 2
#define NBATCH 64
#define TPB 1024           // DIM/16 amps per thread

// ---------------------------------------------------------------------------
// Register-blocked state-vector simulation.
// One block per batch element; full 16384-amp c64 state in 128 KiB LDS.
// Each pass: every thread loads 16 amplitudes spanning a 4-bit index window,
// applies all gates/CNOTs touching only those bits IN REGISTERS, stores back.
// 9 passes total (vs 54 naive sweeps):
//   P1  init product state (layer-1 1q gates in closed form), window {13..10},
//       + L1 CNOTs (b13,b12),(b12,b11),(b11,b10)
//   P2  window {10..7}:  L1 CNOTs (10,9),(9,8),(8,7)
//   P3  window {7..4}:   L1 CNOTs (7,6),(6,5),(5,4)
//   P4  window {4..1}:   L1 CNOTs (4,3),(3,2),(2,1)
//   P5  window {3..0}:   L1 CNOT (1,0), then L2 gates on bits 3..0 (q10..q13)
//   P6  window {13..10}: L2 gates bits 13..10 (q0..q3) + CNOTs (13,12),(12,11),(11,10)
//   P7  window {10..7}:  L2 gates bits 9..7 (q4..q6) + CNOTs (10,9),(9,8),(8,7)
//   P8  window {7..4}:   L2 gates bits 6..4 (q7..q9) + CNOTs (7,6),(6,5),(5,4)
//   P9  window {4..1}:   L2 CNOTs (4,3),(3,2),(2,1)
// L2's final CNOT (b1,b0) is absorbed into the reduction parity:
//   parity_eff(k) = popcount(k) ^ bit1(k).
// LDS layout is XOR-swizzled (linear involution, only low 4 bits touched):
//   phys(k) = k ^ ((k>>4)&15) ^ ((k>>8)&15) ^ ((k>>12)&3)
// which spreads every pass's b64 access pattern across all bank pairs.
// ---------------------------------------------------------------------------

__device__ __host__ constexpr int swiz(int k) {
    return k ^ ((k >> 4) & 15) ^ ((k >> 8) & 15) ^ ((k >> 12) & 3);
}

template<int W>
__device__ __forceinline__ int baseidx(int t) {
    // distribute thread id bits around the 4-bit window at bit position W
    return ((t >> W) << (W + 4)) | (t & ((1 << W) - 1));
}

__device__ __forceinline__ float2 cmul(float2 a, float2 b) {
    return make_float2(a.x * b.x - a.y * b.y, a.x * b.y + a.y * b.x);
}

template<int W>
__device__ __forceinline__ void load16(const float2* __restrict__ s, int pb, float2 r[16]) {
#pragma unroll
    for (int j = 0; j < 16; ++j) r[j] = s[pb ^ swiz(j << W)];
}

template<int W>
__device__ __forceinline__ void store16(float2* __restrict__ s, int pb, const float2 r[16]) {
#pragma unroll
    for (int j = 0; j < 16; ++j) s[pb ^ swiz(j << W)] = r[j];
}

// fused 2x2 gate on local bit B of the 16-amp register group
template<int B>
__device__ __forceinline__ void apply_gate(float2 r[16], float2 g00, float2 g01,
                                           float2 g10, float2 g11) {
#pragma unroll
    for (int j = 0; j < 16; ++j) {
        if (j & (1 << B)) continue;
        const float2 a = r[j];
        const float2 c = r[j | (1 << B)];
        float2 n0, n1;
        n0.x = g00.x * a.x - g00.y * a.y + g01.x * c.x - g01.y * c.y;
        n0.y = g00.x * a.y + g00.y * a.x + g01.x * c.y + g01.y * c.x;
        n1.x = g10.x * a.x - g10.y * a.y + g11.x * c.x - g11.y * c.y;
        n1.y = g10.x * a.y + g10.y * a.x + g11.x * c.y + g11.y * c.x;
        r[j] = n0;
        r[j | (1 << B)] = n1;
    }
}

// CNOT: local control bit C, local target bit T (register permutation -> free)
template<int C, int T>
__device__ __forceinline__ void apply_cnot(float2 r[16]) {
#pragma unroll
    for (int j = 0; j < 16; ++j) {
        if ((j & (1 << C)) && !(j & (1 << T))) {
            const float2 tmp = r[j];
            r[j] = r[j | (1 << T)];
            r[j | (1 << T)] = tmp;
        }
    }
}

template<int W>
__device__ __forceinline__ void cnot_pass(float2* __restrict__ s, int t, float2 r[16]) {
    const int pb = swiz(baseidx<W>(t));
    load16<W>(s, pb, r);
    apply_cnot<3, 2>(r);
    apply_cnot<2, 1>(r);
    apply_cnot<1, 0>(r);
    store16<W>(s, pb, r);
}

template<int B>
__device__ __forceinline__ void gate_lq(float2 r[16], const float2* gm, int layer, int q) {
    const float2* g = &gm[(layer * NQ + q) * 4];
    apply_gate<B>(r, g[0], g[1], g[2], g[3]);
}

__global__ __launch_bounds__(TPB) void qsim_kernel(
    const float* __restrict__ x,
    const float* __restrict__ thetas,
    float* __restrict__ out)
{
    extern __shared__ float2 s[];              // DIM swizzled amplitudes
    __shared__ float2 gmat[NL * NQ * 4];       // fused 2x2: g00,g01,g10,g11
    __shared__ float redbuf[TPB / 64];

    const int b   = blockIdx.x;
    const int tid = threadIdx.x;
    const float xv = x[b];

    // ---- build fused gates U = RX(t2) RZ(t1) RX(t0) RZ(x2) RY(x1), one thread per (layer,q)
    if (tid < NL * NQ) {
        const int layer = tid / NQ, q = tid % NQ;
        const float x1 = asinf(xv);
        const float x2 = acosf(xv * xv);
        float c1, s1; sincosf(0.5f * x1, &s1, &c1);
        float2 g[4];
        g[0] = make_float2(c1, 0.f);  g[1] = make_float2(-s1, 0.f);
        g[2] = make_float2(s1, 0.f);  g[3] = make_float2(c1, 0.f);
        auto lmul_rz = [&](float t) {
            float cc, ss; sincosf(0.5f * t, &ss, &cc);
            for (int col = 0; col < 2; ++col) {
                float2 a = g[col];
                float2 d = g[2 + col];
                g[col]     = make_float2(cc * a.x + ss * a.y, cc * a.y - ss * a.x);
                g[2 + col] = make_float2(cc * d.x - ss * d.y, cc * d.y + ss * d.x);
            }
        };
        auto lmul_rx = [&](float t) {
            float cc, ss; sincosf(0.5f * t, &ss, &cc);
            for (int col = 0; col < 2; ++col) {
                float2 a = g[col];
                float2 d = g[2 + col];
                g[col]     = make_float2(cc * a.x + ss * d.y,  cc * a.y - ss * d.x);
                g[2 + col] = make_float2(ss * a.y + cc * d.x, -ss * a.x + cc * d.y);
            }
        };
        const float t0 = thetas[(layer * NQ + q) * 3 + 0];
        const float t1 = thetas[(layer * NQ + q) * 3 + 1];
        const float t2 = thetas[(layer * NQ + q) * 3 + 2];
        lmul_rz(x2); lmul_rx(t0); lmul_rz(t1); lmul_rx(t2);
        gmat[tid * 4 + 0] = g[0]; gmat[tid * 4 + 1] = g[1];
        gmat[tid * 4 + 2] = g[2]; gmat[tid * 4 + 3] = g[3];
    }
    __syncthreads();

    float2 r[16];

    // ---- P1: product-state init (layer 1 = 1q gates applied to |0..0>),
    //          window {13..10} local, + L1 CNOTs (13,12),(12,11),(11,10)
    {
        // local factor table by doubling: local bit l <-> global bit 10+l <-> qubit 3-l
        r[0] = make_float2(1.f, 0.f);
#pragma unroll
        for (int l = 0; l < 4; ++l) {
            const int q = 3 - l;
            const float2 c0 = gmat[q * 4 + 0];   // col0 row0 (layer 0)
            const float2 c1 = gmat[q * 4 + 2];   // col0 row1
#pragma unroll
            for (int m = (1 << 3) - 1; m >= 0; --m) {   // iterate high->low so r[m] still valid
                if (m < (1 << l)) {
                    r[m | (1 << l)] = cmul(r[m], c1);
                    r[m] = cmul(r[m], c0);
                }
            }
        }
        // common factor over thread bits 9..0 (global bits 9..0 <-> qubits 13..4)
        float2 common = make_float2(1.f, 0.f);
#pragma unroll
        for (int bb = 0; bb < 10; ++bb) {
            const int q = 13 - bb;
            const float2 f = gmat[q * 4 + (((tid >> bb) & 1) ? 2 : 0)];
            common = cmul(common, f);
        }
#pragma unroll
        for (int j = 0; j < 16; ++j) r[j] = cmul(r[j], common);

        apply_cnot<3, 2>(r);   // CNOT bits (13,12)
        apply_cnot<2, 1>(r);   // (12,11)
        apply_cnot<1, 0>(r);   // (11,10)
        const int pb = swiz(baseidx<10>(tid));
        store16<10>(s, pb, r);
    }
    __syncthreads();

    // ---- P2..P4: remaining L1 CNOT chain
    cnot_pass<7>(s, tid, r);  __syncthreads();   // (10,9),(9,8),(8,7)
    cnot_pass<4>(s, tid, r);  __syncthreads();   // (7,6),(6,5),(5,4)
    cnot_pass<1>(s, tid, r);  __syncthreads();   // (4,3),(3,2),(2,1)

    // ---- P5: window {3..0}: L1 CNOT (1,0), then L2 gates bits 3..0 = q10..q13
    {
        const int pb = swiz(baseidx<0>(tid));
        load16<0>(s, pb, r);
        apply_cnot<1, 0>(r);
        gate_lq<3>(r, gmat, 1, 10);
        gate_lq<2>(r, gmat, 1, 11);
        gate_lq<1>(r, gmat, 1, 12);
        gate_lq<0>(r, gmat, 1, 13);
        store16<0>(s, pb, r);
    }
    __syncthreads();

    // ---- P6: window {13..10}: L2 gates q0..q3 (bits 13..10) + CNOTs
    {
        const int pb = swiz(baseidx<10>(tid));
        load16<10>(s, pb, r);
        gate_lq<3>(r, gmat, 1, 0);
        gate_lq<2>(r, gmat, 1, 1);
        gate_lq<1>(r, gmat, 1, 2);
        gate_lq<0>(r, gmat, 1, 3);
        apply_cnot<3, 2>(r);
        apply_cnot<2, 1>(r);
        apply_cnot<1, 0>(r);
        store16<10>(s, pb, r);
    }
    __syncthreads();

    // ---- P7: window {10..7}: L2 gates bits 9,8,7 (q4,q5,q6) + CNOTs (10,9),(9,8),(8,7)
    {
        const int pb = swiz(baseidx<7>(tid));
        load16<7>(s, pb, r);
        gate_lq<2>(r, gmat, 1, 4);
        gate_lq<1>(r, gmat, 1, 5);
        gate_lq<0>(r, gmat, 1, 6);
        apply_cnot<3, 2>(r);
        apply_cnot<2, 1>(r);
        apply_cnot<1, 0>(r);
        store16<7>(s, pb, r);
    }
    __syncthreads();

    // ---- P8: window {7..4}: L2 gates bits 6,5,4 (q7,q8,q9) + CNOTs (7,6),(6,5),(5,4)
    {
        const int pb = swiz(baseidx<4>(tid));
        load16<4>(s, pb, r);
        gate_lq<2>(r, gmat, 1, 7);
        gate_lq<1>(r, gmat, 1, 8);
        gate_lq<0>(r, gmat, 1, 9);
        apply_cnot<3, 2>(r);
        apply_cnot<2, 1>(r);
        apply_cnot<1, 0>(r);
        store16<4>(s, pb, r);
    }
    __syncthreads();

    // ---- P9: window {4..1}: L2 CNOTs (4,3),(3,2),(2,1)
    cnot_pass<1>(s, tid, r);
    __syncthreads();

    // ---- reduction: <Z^14> with L2's final CNOT (1,0) folded into parity:
    //      sign(k) = (-1)^(popcount(k) ^ bit1(k))
    float acc = 0.f;
#pragma unroll
    for (int i = 0; i < DIM / TPB; ++i) {
        const int p = tid + i * TPB;           // physical slot; holds amp k = swiz(p)
        const float2 a = s[p];
        const int k = swiz(p);
        const float p2 = a.x * a.x + a.y * a.y;
        acc += ((__popc(k) + (k >> 1)) & 1) ? -p2 : p2;
    }
    for (int off = 32; off > 0; off >>= 1)
        acc += __shfl_down(acc, off, 64);
    const int lane = tid & 63, wid = tid >> 6;
    if (lane == 0) redbuf[wid] = acc;
    __syncthreads();
    if (tid == 0) {
        float tot = 0.f;
        for (int w = 0; w < TPB / 64; ++w) tot += redbuf[w];
        out[b] = tot;
    }
}

extern "C" void kernel_launch(void* const* d_in, const int* in_sizes, int n_in,
                              void* d_out, int out_size, void* d_ws, size_t ws_size,
                              hipStream_t stream) {
    const float* x      = (const float*)d_in[0];
    const float* thetas = (const float*)d_in[1];
    float* out          = (float*)d_out;
    const size_t shmem = (size_t)DIM * sizeof(float2);   // 128 KiB dynamic LDS
    qsim_kernel<<<NBATCH, TPB, shmem, stream>>>(x, thetas, out);
}

// Round 3
// 74.085 us; speedup vs baseline: 1.6756x; 1.3166x over previous
//
#include <hip/hip_runtime.h>
#include <math.h>

#define NQ 14
#define DIM (1 << NQ)      // 16384
#define NL 2
#define NBATCH 64
#define TPB 1024           // DIM/16 amps per thread

// ---------------------------------------------------------------------------
// Register-blocked state-vector simulation, layer-1 in closed form.
//
// Algebra:
//  * Per (layer,q) the 5 single-qubit gates fuse to one 2x2:
//      U = RX(t2) RZ(t1) RX(t0) RZ(x2) RY(x1).
//  * Layer 1 = 1q gates on |0..0> -> product state; its CNOT chain
//    (q->q+1, q=0..12) is the linear index map sigma with
//    sigma^{-1}(k) = k ^ (k>>1) (Gray code). So the full post-layer-1 state
//    is closed-form:  amp(k) = prod_p f_{13-p}( bit_p(k) ^ bit_{p+1}(k) ),
//    f_q(b) = column-0 row-b of layer-0 fused gate. Computed at init,
//    ZERO LDS sweeps for layer 1.
//  * Layer-2 CNOT chain folds into the measurement parity:
//    popcount(sigma(k)) mod 2 = popcount(k & 0x1555) mod 2
//    (sum_i (i+1) b_i mod 2 -> even bit positions).
//
// Schedule (4 passes, 3 barriers), window = 4 local index bits:
//   A: init closed-form + L2 gates q0..q3  (bits 13..10), store
//   B: load {9..6},  L2 gates q4..q7,  store
//   C: load {5..2},  L2 gates q8..q11, store
//   D: load {3..0},  L2 gates q12,q13, fused signed reduction (no store)
//
// LDS layout XOR-swizzled (linear involution): phys(k) = swiz(k); every
// pass's b64 pattern hits each bank-pair exactly 4x (the b64 floor).
//
// __launch_bounds__(1024, 4): 4 waves/EU min -> VGPR cap 128 (not 64) so
// r[16] stays in registers. Round-2 lesson: default budget (64 VGPR) spilled
// 24.5 MB/dispatch to scratch.
// ---------------------------------------------------------------------------

__device__ __host__ constexpr int swiz(int k) {
    return k ^ ((k >> 4) & 15) ^ ((k >> 8) & 15) ^ ((k >> 12) & 3);
}

template<int W>
__device__ __forceinline__ int baseidx(int t) {
    return ((t >> W) << (W + 4)) | (t & ((1 << W) - 1));
}

__device__ __forceinline__ float2 cmul(float2 a, float2 b) {
    return make_float2(a.x * b.x - a.y * b.y, a.x * b.y + a.y * b.x);
}

template<int W>
__device__ __forceinline__ void load16(const float2* __restrict__ s, int pb, float2 r[16]) {
#pragma unroll
    for (int j = 0; j < 16; ++j) r[j] = s[pb ^ swiz(j << W)];
}

template<int W>
__device__ __forceinline__ void store16(float2* __restrict__ s, int pb, const float2 r[16]) {
#pragma unroll
    for (int j = 0; j < 16; ++j) s[pb ^ swiz(j << W)] = r[j];
}

// fused 2x2 gate on local bit B of the 16-amp register group
template<int B>
__device__ __forceinline__ void apply_gate(float2 r[16], float2 g00, float2 g01,
                                           float2 g10, float2 g11) {
#pragma unroll
    for (int j = 0; j < 16; ++j) {
        if (j & (1 << B)) continue;
        const float2 a = r[j];
        const float2 c = r[j | (1 << B)];
        float2 n0, n1;
        n0.x = g00.x * a.x - g00.y * a.y + g01.x * c.x - g01.y * c.y;
        n0.y = g00.x * a.y + g00.y * a.x + g01.x * c.y + g01.y * c.x;
        n1.x = g10.x * a.x - g10.y * a.y + g11.x * c.x - g11.y * c.y;
        n1.y = g10.x * a.y + g10.y * a.x + g11.x * c.y + g11.y * c.x;
        r[j] = n0;
        r[j | (1 << B)] = n1;
    }
}

template<int B>
__device__ __forceinline__ void gate_lq(float2 r[16], const float2* gm, int layer, int q) {
    const float2* g = &gm[(layer * NQ + q) * 4];
    apply_gate<B>(r, g[0], g[1], g[2], g[3]);
}

__global__ __launch_bounds__(TPB, 4) void qsim_kernel(
    const float* __restrict__ x,
    const float* __restrict__ thetas,
    float* __restrict__ out)
{
    extern __shared__ float2 s[];              // DIM swizzled amplitudes
    __shared__ float2 gmat[NL * NQ * 4];       // fused 2x2: g00,g01,g10,g11
    __shared__ float redbuf[TPB / 64];

    const int b   = blockIdx.x;
    const int tid = threadIdx.x;
    const float xv = x[b];

    // ---- build fused gates U = RX(t2) RZ(t1) RX(t0) RZ(x2) RY(x1)
    if (tid < NL * NQ) {
        const int layer = tid / NQ, q = tid % NQ;
        const float x1 = asinf(xv);
        const float x2 = acosf(xv * xv);
        float c1, s1; sincosf(0.5f * x1, &s1, &c1);
        float2 g[4];
        g[0] = make_float2(c1, 0.f);  g[1] = make_float2(-s1, 0.f);
        g[2] = make_float2(s1, 0.f);  g[3] = make_float2(c1, 0.f);
        auto lmul_rz = [&](float t) {
            float cc, ss; sincosf(0.5f * t, &ss, &cc);
            for (int col = 0; col < 2; ++col) {
                float2 a = g[col];
                float2 d = g[2 + col];
                g[col]     = make_float2(cc * a.x + ss * a.y, cc * a.y - ss * a.x);
                g[2 + col] = make_float2(cc * d.x - ss * d.y, cc * d.y + ss * d.x);
            }
        };
        auto lmul_rx = [&](float t) {
            float cc, ss; sincosf(0.5f * t, &ss, &cc);
            for (int col = 0; col < 2; ++col) {
                float2 a = g[col];
                float2 d = g[2 + col];
                g[col]     = make_float2(cc * a.x + ss * d.y,  cc * a.y - ss * d.x);
                g[2 + col] = make_float2(ss * a.y + cc * d.x, -ss * a.x + cc * d.y);
            }
        };
        const float t0 = thetas[(layer * NQ + q) * 3 + 0];
        const float t1 = thetas[(layer * NQ + q) * 3 + 1];
        const float t2 = thetas[(layer * NQ + q) * 3 + 2];
        lmul_rz(x2); lmul_rx(t0); lmul_rz(t1); lmul_rx(t2);
        gmat[tid * 4 + 0] = g[0]; gmat[tid * 4 + 1] = g[1];
        gmat[tid * 4 + 2] = g[2]; gmat[tid * 4 + 3] = g[3];
    }
    __syncthreads();

    // f_q(b): column 0, row b of layer-0 fused gate q
    auto f0c = [&](int q, int bb) -> float2 { return gmat[q * 4 + (bb ? 2 : 0)]; };

    float2 r[16];

    // ---- Pass A: closed-form post-layer-1 state, window {13..10},
    //      then L2 gates q0..q3, store.
    //  amp(k) = prod_{p=0..13} f_{13-p}(bit_p(k) ^ bit_{p+1}(k)), k=(loc<<10)|tid
    {
        const int gt = tid ^ (tid >> 1);       // bit p (p<=8): t_p ^ t_{p+1}
        float2 common = f0c(13, gt & 1);       // p=0 -> qubit 13
#pragma unroll
        for (int p = 1; p <= 8; ++p)
            common = cmul(common, f0c(13 - p, (gt >> p) & 1));
        const int t9 = (tid >> 9) & 1;
        const float2 pre0 = cmul(common, f0c(4, t9));      // p=9: t9 ^ loc0
        const float2 pre1 = cmul(common, f0c(4, t9 ^ 1));

        // doubling over loc bits 3..0 (loc bit l <-> global bit 10+l <-> factor f_{3-l})
        r[0] = f0c(0, 0);                      // p=13 -> f_0(loc3)
        r[8] = f0c(0, 1);
#pragma unroll
        for (int l = 2; l >= 0; --l) {
#pragma unroll
            for (int m = 0; m < 16; ++m) {
                if ((m & ((1 << (l + 1)) - 1)) == 0) {
                    const int bh = (m >> (l + 1)) & 1;     // bit_{l+1}
                    r[m | (1 << l)] = cmul(f0c(3 - l, bh ^ 1), r[m]);
                    r[m]            = cmul(f0c(3 - l, bh),     r[m]);
                }
            }
        }
#pragma unroll
        for (int m = 0; m < 16; ++m)
            r[m] = cmul((m & 1) ? pre1 : pre0, r[m]);

        // L2 gates on bits 13..10: qubit 0<->local bit 3, ..., qubit 3<->local bit 0
        gate_lq<3>(r, gmat, 1, 0);
        gate_lq<2>(r, gmat, 1, 1);
        gate_lq<1>(r, gmat, 1, 2);
        gate_lq<0>(r, gmat, 1, 3);
        store16<10>(s, swiz(baseidx<10>(tid)), r);
    }
    __syncthreads();

    // ---- Pass B: window {9..6}: L2 gates q4..q7
    {
        const int pb = swiz(baseidx<6>(tid));
        load16<6>(s, pb, r);
        gate_lq<3>(r, gmat, 1, 4);
        gate_lq<2>(r, gmat, 1, 5);
        gate_lq<1>(r, gmat, 1, 6);
        gate_lq<0>(r, gmat, 1, 7);
        store16<6>(s, pb, r);
    }
    __syncthreads();

    // ---- Pass C: window {5..2}: L2 gates q8..q11
    {
        const int pb = swiz(baseidx<2>(tid));
        load16<2>(s, pb, r);
        gate_lq<3>(r, gmat, 1, 8);
        gate_lq<2>(r, gmat, 1, 9);
        gate_lq<1>(r, gmat, 1, 10);
        gate_lq<0>(r, gmat, 1, 11);
        store16<2>(s, pb, r);
    }
    __syncthreads();

    // ---- Pass D: window {3..0}: L2 gates q12,q13 + fused signed reduction.
    //      L2 CNOT chain folded into parity: sign(k) = (-1)^popcount(k & 0x1555)
    float acc = 0.f;
    {
        const int pb = swiz(baseidx<0>(tid));
        load16<0>(s, pb, r);
        gate_lq<1>(r, gmat, 1, 12);
        gate_lq<0>(r, gmat, 1, 13);
        const int st = __popc(tid & 0x155) & 1;   // parity of even global bits >=4
#pragma unroll
        for (int j = 0; j < 16; ++j) {
            const float p2 = r[j].x * r[j].x + r[j].y * r[j].y;
            acc += ((st ^ (__popc(j & 5) & 1)) ? -p2 : p2);
        }
    }

    // ---- block reduction
    for (int off = 32; off > 0; off >>= 1)
        acc += __shfl_down(acc, off, 64);
    const int lane = tid & 63, wid = tid >> 6;
    if (lane == 0) redbuf[wid] = acc;
    __syncthreads();
    if (tid == 0) {
        float tot = 0.f;
        for (int w = 0; w < TPB / 64; ++w) tot += redbuf[w];
        out[b] = tot;
    }
}

extern "C" void kernel_launch(void* const* d_in, const int* in_sizes, int n_in,
                              void* d_out, int out_size, void* d_ws, size_t ws_size,
                              hipStream_t stream) {
    const float* x      = (const float*)d_in[0];
    const float* thetas = (const float*)d_in[1];
    float* out          = (float*)d_out;
    const size_t shmem = (size_t)DIM * sizeof(float2);   // 128 KiB dynamic LDS
    qsim_kernel<<<NBATCH, TPB, shmem, stream>>>(x, thetas, out);
}

// Round 4
// 61.479 us; speedup vs baseline: 2.0192x; 1.2050x over previous
//
#include <hip/hip_runtime.h>
#include <math.h>

#define NQ 14
#define DIM (1 << NQ)          // 16384
#define NL 2
#define NBATCH 64
#define TPB 256
#define BPB 4                  // blocks per batch element (split bits 13,11)
#define APB 4096               // amps per block (12 free bits)

// ---------------------------------------------------------------------------
// Round-4 structure: 256 blocks (1/CU), 4 per batch element, 4096 amps each.
//
// Algebra (items 1-3 verified by round-3 pass, absmax 6e-8):
//  1. Fused per-(layer,q) 2x2:  U = RX(t2) RZ(t1) RX(t0) RZ(x2) RY(x1).
//  2. Post-layer-1 state is closed-form (product state through the Gray-code
//     CNOT permutation):  amp(k) = prod_{p=0..13} f_{13-p}(bit_p ^ bit_{p+1}),
//     f_q(b) = column-0 row-b of layer-0 fused gate q.
//  3. L2 CNOT chain folds into measurement parity: sign(k)=(-1)^popc(k&0x1555).
//  4. NEW: parity support = bits {0,2,4,6,8,10,12} = qubits {13,11,9,7,5,3,1}.
//     L2 gates on the OTHER 7 qubits conjugate identity -> dropped entirely.
//  5. Remaining gate bits {6,8,10,12} and {0,2,4} form two register windows;
//     bits 11,13 appear in neither -> block-split bits. Zero cross-block comm:
//     pass A = closed-form init + gates q7,q5,q3,q1 + LDS store;
//     pass B = LDS load + gates q13,q11,q9 + signed reduce + atomicAdd.
//
// LDS swizzle phys(q) = q ^ ((q>>6)&63) (XOR-linear). Lane maps chosen so both
// passes give 64 distinct phys-low-6 per instruction = b64 bank floor.
// __launch_bounds__(256,1): VGPR cap 512, no spill (round-2 lesson).
// ---------------------------------------------------------------------------

__device__ __host__ constexpr int physx(int q) { return q ^ ((q >> 6) & 0x3F); }

__device__ __forceinline__ float2 cmul(float2 a, float2 b) {
    return make_float2(a.x * b.x - a.y * b.y, a.x * b.y + a.y * b.x);
}

// fused 2x2 gate on local bit B of the 16-amp register group
template<int B>
__device__ __forceinline__ void apply_gate(float2 r[16], float2 g00, float2 g01,
                                           float2 g10, float2 g11) {
#pragma unroll
    for (int j = 0; j < 16; ++j) {
        if (j & (1 << B)) continue;
        const float2 a = r[j];
        const float2 c = r[j | (1 << B)];
        float2 n0, n1;
        n0.x = g00.x * a.x - g00.y * a.y + g01.x * c.x - g01.y * c.y;
        n0.y = g00.x * a.y + g00.y * a.x + g01.x * c.y + g01.y * c.x;
        n1.x = g10.x * a.x - g10.y * a.y + g11.x * c.x - g11.y * c.y;
        n1.y = g10.x * a.y + g10.y * a.x + g11.x * c.y + g11.y * c.x;
        r[j] = n0;
        r[j | (1 << B)] = n1;
    }
}

template<int B>
__device__ __forceinline__ void gate_lq(float2 r[16], const float2* gm, int q) {
    const float2* g = &gm[(NQ + q) * 4];   // layer-1 fused gate q
    apply_gate<B>(r, g[0], g[1], g[2], g[3]);
}

__global__ __launch_bounds__(TPB, 1) void qsim_kernel(
    const float* __restrict__ x,
    const float* __restrict__ thetas,
    float* __restrict__ out)
{
    __shared__ float2 s[APB];              // 32 KiB, swizzled block slice
    __shared__ float2 gmat[NL * NQ * 4];
    __shared__ float redbuf[TPB / 64];

    const int bid = blockIdx.x;
    const int b   = bid >> 2;
    const int K11 = bid & 1;               // global bit 11
    const int K13 = (bid >> 1) & 1;        // global bit 13
    const int tid = threadIdx.x;
    const float xv = x[b];

    // ---- build fused gates U = RX(t2) RZ(t1) RX(t0) RZ(x2) RY(x1)
    if (tid < NL * NQ) {
        const int layer = tid / NQ, q = tid % NQ;
        const float x1 = asinf(xv);
        const float x2 = acosf(xv * xv);
        float c1, s1; sincosf(0.5f * x1, &s1, &c1);
        float2 g[4];
        g[0] = make_float2(c1, 0.f);  g[1] = make_float2(-s1, 0.f);
        g[2] = make_float2(s1, 0.f);  g[3] = make_float2(c1, 0.f);
        auto lmul_rz = [&](float t) {
            float cc, ss; sincosf(0.5f * t, &ss, &cc);
            for (int col = 0; col < 2; ++col) {
                float2 a = g[col];
                float2 d = g[2 + col];
                g[col]     = make_float2(cc * a.x + ss * a.y, cc * a.y - ss * a.x);
                g[2 + col] = make_float2(cc * d.x - ss * d.y, cc * d.y + ss * d.x);
            }
        };
        auto lmul_rx = [&](float t) {
            float cc, ss; sincosf(0.5f * t, &ss, &cc);
            for (int col = 0; col < 2; ++col) {
                float2 a = g[col];
                float2 d = g[2 + col];
                g[col]     = make_float2(cc * a.x + ss * d.y,  cc * a.y - ss * d.x);
                g[2 + col] = make_float2(ss * a.y + cc * d.x, -ss * a.x + cc * d.y);
            }
        };
        const float t0 = thetas[(layer * NQ + q) * 3 + 0];
        const float t1 = thetas[(layer * NQ + q) * 3 + 1];
        const float t2 = thetas[(layer * NQ + q) * 3 + 2];
        lmul_rz(x2); lmul_rx(t0); lmul_rz(t1); lmul_rx(t2);
        gmat[tid * 4 + 0] = g[0]; gmat[tid * 4 + 1] = g[1];
        gmat[tid * 4 + 2] = g[2]; gmat[tid * 4 + 3] = g[3];
    }
    __syncthreads();

    // f_q(b): column 0, row b of layer-0 fused gate q
    auto f0c = [&](int q, int bb) -> float2 { return gmat[q * 4 + (bb ? 2 : 0)]; };

    float2 r[16];

    // ---- Pass A: closed-form init, local bits {6,8,10,12} (m0..m3),
    //      thread bits: t0..t5 -> k0..k5, t6 -> k7, t7 -> k9.
    {
        const int b0 = tid & 1, b1 = (tid >> 1) & 1, b2 = (tid >> 2) & 1;
        const int b3 = (tid >> 3) & 1, b4 = (tid >> 4) & 1, b5 = (tid >> 5) & 1;
        const int b7 = (tid >> 6) & 1, b9 = (tid >> 7) & 1;

        float2 common = f0c(13, b0 ^ b1);          // p=0
        common = cmul(common, f0c(12, b1 ^ b2));   // p=1
        common = cmul(common, f0c(11, b2 ^ b3));   // p=2
        common = cmul(common, f0c(10, b3 ^ b4));   // p=3
        common = cmul(common, f0c(9,  b4 ^ b5));   // p=4
        common = cmul(common, f0c(0,  K13));       // p=13

        float2 h6[2], h8[2], h10[2], h12[2];
#pragma unroll
        for (int v = 0; v < 2; ++v) {
            h6[v]  = cmul(f0c(8, b5 ^ v),  f0c(7, v ^ b7));   // p=5,6
            h8[v]  = cmul(f0c(6, b7 ^ v),  f0c(5, v ^ b9));   // p=7,8
            h10[v] = cmul(f0c(4, b9 ^ v),  f0c(3, v ^ K11));  // p=9,10
            h12[v] = cmul(f0c(2, K11 ^ v), f0c(1, v ^ K13));  // p=11,12
        }
        r[0] = cmul(common, h6[0]);
        r[1] = cmul(common, h6[1]);
#pragma unroll
        for (int m = 0; m < 2; ++m) { r[m | 2] = cmul(r[m], h8[1]);  r[m] = cmul(r[m], h8[0]); }
#pragma unroll
        for (int m = 0; m < 4; ++m) { r[m | 4] = cmul(r[m], h10[1]); r[m] = cmul(r[m], h10[0]); }
#pragma unroll
        for (int m = 0; m < 8; ++m) { r[m | 8] = cmul(r[m], h12[1]); r[m] = cmul(r[m], h12[0]); }

        // L2 gates: m0<->bit6<->q7, m1<->bit8<->q5, m2<->bit10<->q3, m3<->bit12<->q1
        gate_lq<0>(r, gmat, 7);
        gate_lq<1>(r, gmat, 5);
        gate_lq<2>(r, gmat, 3);
        gate_lq<3>(r, gmat, 1);

        // store; within-block index q: q0..q10 = k0..k10, q11 = k12
        const int qbase = (tid & 63) | (b7 << 7) | (b9 << 9);
        const int pb = physx(qbase);
#pragma unroll
        for (int m = 0; m < 16; ++m) {
            const int off = ((m & 1) << 6) | (((m >> 1) & 1) << 8) |
                            (((m >> 2) & 1) << 10) | (((m >> 3) & 1) << 11);
            s[pb ^ physx(off)] = r[m];
        }
    }
    __syncthreads();

    // ---- Pass B: local bits {0,1,2,4} (j0..j3), gates q13,q11,q9 + reduce.
    //      thread bits: t0..t4 -> k6..k10, t5 -> k5, t6 -> k3, t7 -> k12.
    float acc = 0.f;
    {
        const int t0 = tid & 1, t1 = (tid >> 1) & 1, t2 = (tid >> 2) & 1;
        const int t3 = (tid >> 3) & 1, t4 = (tid >> 4) & 1, t5 = (tid >> 5) & 1;
        const int t6 = (tid >> 6) & 1, t7 = (tid >> 7) & 1;
        const int qbase = (t6 << 3) | (t5 << 5) | (t0 << 6) | (t1 << 7) |
                          (t2 << 8) | (t3 << 9) | (t4 << 10) | (t7 << 11);
        const int pb = physx(qbase);
#pragma unroll
        for (int j = 0; j < 16; ++j) {
            const int off = (j & 7) | (((j >> 3) & 1) << 4);   // bits {0,1,2,4}
            r[j] = s[pb ^ off];                                 // physx(off)=off (low bits)
        }
        // j0<->bit0<->q13, j2<->bit2<->q11, j3<->bit4<->q9 (j1 = spare bit1)
        gate_lq<0>(r, gmat, 13);
        gate_lq<2>(r, gmat, 11);
        gate_lq<3>(r, gmat, 9);

        // sign(k) = (-1)^popc(k & 0x1555); fixed bits {6,8,10,12} = t0,t2,t4,t7
        const int st = __popc(tid & 0x95) & 1;
#pragma unroll
        for (int j = 0; j < 16; ++j) {
            const float p2 = r[j].x * r[j].x + r[j].y * r[j].y;
            acc += ((st ^ (__popc(j & 13) & 1)) ? -p2 : p2);   // j bits {0,2,3}
        }
    }

    // ---- block reduction + atomic combine across the 4 sibling blocks
    for (int off = 32; off > 0; off >>= 1)
        acc += __shfl_down(acc, off, 64);
    const int lane = tid & 63, wid = tid >> 6;
    if (lane == 0) redbuf[wid] = acc;
    __syncthreads();
    if (tid == 0) {
        float tot = redbuf[0] + redbuf[1] + redbuf[2] + redbuf[3];
        atomicAdd(&out[b], tot);
    }
}

extern "C" void kernel_launch(void* const* d_in, const int* in_sizes, int n_in,
                              void* d_out, int out_size, void* d_ws, size_t ws_size,
                              hipStream_t stream) {
    const float* x      = (const float*)d_in[0];
    const float* thetas = (const float*)d_in[1];
    float* out          = (float*)d_out;
    hipMemsetAsync(out, 0, NBATCH * sizeof(float), stream);   // atomicAdd target
    qsim_kernel<<<NBATCH * BPB, TPB, 0, stream>>>(x, thetas, out);
}

// Round 5
// 58.020 us; speedup vs baseline: 2.1396x; 1.0596x over previous
//
#include <hip/hip_runtime.h>
#include <math.h>

#define NQ 14
#define NL 2
#define NBATCH 64
#define TPB 64

// ---------------------------------------------------------------------------
// Round-5: closed-form transfer-matrix evaluation. The state vector is never
// materialized.
//
// Verified algebra chain (rounds 3-4 passed on HW, absmax ~1e-7):
//  1. Per (layer,q) the 5 single-qubit gates fuse: U = RX(t2)RZ(t1)RX(t0)RZ(x2)RY(x1).
//  2. Post-layer-1 state (1q product state through the Gray-code CNOT chain):
//       psi(b) = prod_{p=0..13} f_{13-p}(b_p ^ b_{p+1}),  b_14 = 0,
//     f_q(v) = column-0 row-v of layer-0 fused gate q.   -> bond-2 MPS.
//  3. L2 CNOT chain folds into the parity: support = even bits = odd qubits.
//  4. L2 gates on even qubits conjugate identity -> dropped. Observable =
//     prod over odd q of M_q = U_q^dag Z U_q  (single-site product operator).
//
// NEW (round 5): <psi| prod O_p |psi> for nearest-neighbor-coupled psi is a
// 4-state transfer-matrix contraction over pairs (b_p, b'_p):
//   F_14 = indicator(0,0)
//   F_p(b,b') = O_p(b,b') * sum_{s,s'} conj(g_p(b^s)) g_p(b'^s') F_{p+1}(s,s')
//   with g_p = f_{13-p};  O_p = I (odd p) or M_{13-p} (even p).
//   E = sum_{b,b'} F_0(b,b').
// ~4 kFLOP per batch element total. Checked analytically on 4 closed-form
// circuits (identity->+1, X->-1, H->0, RY(theta)->cos theta).
//
// 64 blocks x 64 threads: lanes 0..20 fuse gates into LDS (uniform fuse body),
// every lane runs the recursion redundantly (wave-uniform), lane 0 writes.
// ---------------------------------------------------------------------------

__device__ __forceinline__ float2 cmul(float2 a, float2 b) {
    return make_float2(a.x * b.x - a.y * b.y, a.x * b.y + a.y * b.x);
}
__device__ __forceinline__ float2 conjmul(float2 a, float2 b) {   // conj(a)*b
    return make_float2(a.x * b.x + a.y * b.y, a.x * b.y - a.y * b.x);
}
__device__ __forceinline__ float2 cadd(float2 a, float2 b) {
    return make_float2(a.x + b.x, a.y + b.y);
}

// fused 2x2: U = RX(t2) RZ(t1) RX(t0) RZ(x2) RY(x1)   (verified rounds 1-4)
__device__ __forceinline__ void fuse_gate(float x1, float x2,
                                          float t0, float t1, float t2,
                                          float2 g[4]) {
    float c1, s1; sincosf(0.5f * x1, &s1, &c1);
    g[0] = make_float2(c1, 0.f);  g[1] = make_float2(-s1, 0.f);
    g[2] = make_float2(s1, 0.f);  g[3] = make_float2(c1, 0.f);
    auto lmul_rz = [&](float t) {
        float cc, ss; sincosf(0.5f * t, &ss, &cc);
        for (int col = 0; col < 2; ++col) {
            float2 a = g[col];
            float2 d = g[2 + col];
            g[col]     = make_float2(cc * a.x + ss * a.y, cc * a.y - ss * a.x);
            g[2 + col] = make_float2(cc * d.x - ss * d.y, cc * d.y + ss * d.x);
        }
    };
    auto lmul_rx = [&](float t) {
        float cc, ss; sincosf(0.5f * t, &ss, &cc);
        for (int col = 0; col < 2; ++col) {
            float2 a = g[col];
            float2 d = g[2 + col];
            g[col]     = make_float2(cc * a.x + ss * d.y,  cc * a.y - ss * d.x);
            g[2 + col] = make_float2(ss * a.y + cc * d.x, -ss * a.x + cc * d.y);
        }
    };
    lmul_rz(x2); lmul_rx(t0); lmul_rz(t1); lmul_rx(t2);
}

__global__ __launch_bounds__(TPB) void qsim_kernel(
    const float* __restrict__ x,
    const float* __restrict__ thetas,
    float* __restrict__ out)
{
    __shared__ float2 sf[NQ][2];   // f_q(0), f_q(1): layer-0 fused gate column 0
    __shared__ float  sm[7][2];    // M_q diag (real): m00, m11 for q = 2i+1
    __shared__ float2 smo[7];      // M_q off-diag m01 (m10 = conj)

    const int b   = blockIdx.x;
    const int tid = threadIdx.x;
    const float xv = x[b];
    const float x1 = asinf(xv);
    const float x2 = acosf(xv * xv);

    // ---- fuse 21 gates: lanes 0..13 -> layer 0 qubit tid;
    //      lanes 14..20 -> layer 1 odd qubit 2*(tid-14)+1
    if (tid < 21) {
        const int layer = (tid < NQ) ? 0 : 1;
        const int q     = (tid < NQ) ? tid : 2 * (tid - NQ) + 1;
        const int base  = (layer * NQ + q) * 3;
        float2 g[4];
        fuse_gate(x1, x2, thetas[base], thetas[base + 1], thetas[base + 2], g);
        if (tid < NQ) {
            sf[tid][0] = g[0];            // row 0, col 0
            sf[tid][1] = g[2];            // row 1, col 0
        } else {
            const int i = tid - NQ;       // q = 2i+1
            // M = U^dag Z U: m_bb' = conj(u_{0b}) u_{0b'} - conj(u_{1b}) u_{1b'}
            sm[i][0] = (g[0].x * g[0].x + g[0].y * g[0].y)
                     - (g[2].x * g[2].x + g[2].y * g[2].y);
            sm[i][1] = (g[1].x * g[1].x + g[1].y * g[1].y)
                     - (g[3].x * g[3].x + g[3].y * g[3].y);
            const float2 a = conjmul(g[0], g[1]);
            const float2 c = conjmul(g[2], g[3]);
            smo[i] = make_float2(a.x - c.x, a.y - c.y);
        }
    }
    __syncthreads();

    // ---- transfer-matrix recursion, p = 13 .. 0 (all lanes, wave-uniform)
    float2 F00 = make_float2(1.f, 0.f);
    float2 F01 = make_float2(0.f, 0.f);
    float2 F10 = make_float2(0.f, 0.f);
    float2 F11 = make_float2(0.f, 0.f);
#pragma unroll
    for (int p = NQ - 1; p >= 0; --p) {
        const float2 g0 = sf[NQ - 1 - p][0];
        const float2 g1 = sf[NQ - 1 - p][1];
        // G[b][s'] = sum_s conj(g(b^s)) F[s][s']
        const float2 G00 = cadd(conjmul(g0, F00), conjmul(g1, F10));
        const float2 G01 = cadd(conjmul(g0, F01), conjmul(g1, F11));
        const float2 G10 = cadd(conjmul(g1, F00), conjmul(g0, F10));
        const float2 G11 = cadd(conjmul(g1, F01), conjmul(g0, F11));
        // H[b][b'] = sum_{s'} g(b'^s') G[b][s']
        const float2 H00 = cadd(cmul(g0, G00), cmul(g1, G01));
        const float2 H01 = cadd(cmul(g1, G00), cmul(g0, G01));
        const float2 H10 = cadd(cmul(g0, G10), cmul(g1, G11));
        const float2 H11 = cadd(cmul(g1, G10), cmul(g0, G11));
        if (p & 1) {
            // O_p = identity: keep diagonal only
            F00 = H00; F11 = H11;
            F01 = make_float2(0.f, 0.f);
            F10 = make_float2(0.f, 0.f);
        } else {
            // O_p = M_{13-p}, qubit 13-p = 2i+1, i = (12-p)/2
            const int i = (12 - p) / 2;
            F00 = make_float2(sm[i][0] * H00.x, sm[i][0] * H00.y);
            F11 = make_float2(sm[i][1] * H11.x, sm[i][1] * H11.y);
            F01 = cmul(smo[i], H01);
            F10 = conjmul(smo[i], H10);      // m10 = conj(m01)
        }
    }

    if (tid == 0)
        out[b] = F00.x + F01.x + F10.x + F11.x;
}

extern "C" void kernel_launch(void* const* d_in, const int* in_sizes, int n_in,
                              void* d_out, int out_size, void* d_ws, size_t ws_size,
                              hipStream_t stream) {
    const float* x      = (const float*)d_in[0];
    const float* thetas = (const float*)d_in[1];
    float* out          = (float*)d_out;
    qsim_kernel<<<NBATCH, TPB, 0, stream>>>(x, thetas, out);
}